// Round 4
// baseline (522.986 us; speedup 1.0000x reference)
//
#include <hip/hip_runtime.h>
#include <hip/hip_cooperative_groups.h>
#include <math.h>

namespace cg = cooperative_groups;

// Quantum circuit collapses analytically:
//   z_w = cos(q_params[w]) * cos(features[w])   (RZ layer = pure phase -> no-op on probs)
//   q_out = [z0, z0*z1, z0*z1*z2, z0*z1*z2*z3]  (CNOT chain = parity of independent bits)
// Then MLP 4->64 (relu) -> 4, batchnorm over batch.
//
// Single cooperative kernel: phase A (load+circuit+MLP, logits in REGISTERS,
// per-block batchnorm partials -> ws), grid.sync(), phase B (every block
// redundantly reduces the 8K partials from L2, computes scale/shift,
// normalizes its register-resident logits, writes out). No k_init, no
// atomics, no logits round-trip, one launch instead of three.

#define IMGS_PER_BLOCK 64

__global__ __launch_bounds__(256, 4) void k_fused(
    const float* __restrict__ x,
    const float* __restrict__ qp,
    const float* __restrict__ W1,
    const float* __restrict__ b1,
    const float* __restrict__ W2,
    const float* __restrict__ b2,
    const float* __restrict__ gamma,
    const float* __restrict__ beta,
    float* __restrict__ out,
    float* __restrict__ part,   // gridDim.x*8 floats in ws
    int B, float invB)
{
    __shared__ float sW1[256];   // [j][w], row-major 64x4
    __shared__ float sW2t[256];  // [j][k]  (transpose of W2 4x64)
    __shared__ float sb1[64];
    __shared__ float sfeat[IMGS_PER_BLOCK][4];
    __shared__ float sred[256];  // phase-A: [0..31]; phase-B: full 256
    __shared__ float sc[4], sh[4];

    const int tid = threadIdx.x;
    sW1[tid]  = W1[tid];
    sW2t[tid] = W2[(tid & 3) * 64 + (tid >> 2)];
    if (tid < 64) sb1[tid] = b1[tid];

    // ---- Phase A1: cooperative pooled-feature load (16 lanes per image) ----
    const int g = tid >> 4, l = tid & 15;
    const int img_base = blockIdx.x * IMGS_PER_BLOCK;

    #pragma unroll
    for (int r = 0; r < 4; ++r) {
        const int li  = r * 16 + g;          // local image 0..63
        const int img = img_base + li;
        float f0 = 0.f, f1 = 0.f, f2 = 0.f, f3 = 0.f;
        if (img < B) {
            const float* xb = x + (size_t)img * 1296;
            #pragma unroll
            for (int k = 0; k < 3; ++k) {
                if (k == 2 && l >= 4) break;          // float4 idx 32..35 only
                const int idx = l + k * 16;
                const int row = (idx * 43) >> 8;      // idx/6 for idx<36
                const int col = idx - 6 * row;
                float4 v = ((const float4*)(xb + row * 36))[col];
                float lo = v.x + v.y, hi = v.z + v.w, tot = lo + hi;
                f0 += (col == 0) ? tot : (col == 1) ? lo : 0.f;
                f1 += (col == 2) ? tot : (col == 1) ? hi : 0.f;
                f2 += (col == 3) ? tot : (col == 4) ? lo : 0.f;
                f3 += (col == 5) ? tot : (col == 4) ? hi : 0.f;
            }
        }
        #pragma unroll
        for (int m = 1; m < 16; m <<= 1) {
            f0 += __shfl_xor(f0, m, 16);
            f1 += __shfl_xor(f1, m, 16);
            f2 += __shfl_xor(f2, m, 16);
            f3 += __shfl_xor(f3, m, 16);
        }
        if (l == 0) {
            sfeat[li][0] = f0; sfeat[li][1] = f1;
            sfeat[li][2] = f2; sfeat[li][3] = f3;
        }
    }
    __syncthreads();

    // ---- Phase A2: circuit + MLP, logits stay in registers (threads 0..63) ----
    float l0 = 0.f, l1 = 0.f, l2 = 0.f, l3 = 0.f;
    const int img = img_base + tid;
    const bool active = (tid < IMGS_PER_BLOCK) && (img < B);
    if (active) {
        const float inv36 = 1.0f / 36.0f;
        float z0 = cosf(qp[0]) * cosf(sfeat[tid][0] * inv36);
        float z1 = cosf(qp[1]) * cosf(sfeat[tid][1] * inv36);
        float z2 = cosf(qp[2]) * cosf(sfeat[tid][2] * inv36);
        float z3 = cosf(qp[3]) * cosf(sfeat[tid][3] * inv36);
        float q0 = z0;
        float q1 = q0 * z1;
        float q2 = q1 * z2;
        float q3 = q2 * z3;

        l0 = b2[0]; l1 = b2[1]; l2 = b2[2]; l3 = b2[3];
        #pragma unroll 8
        for (int j = 0; j < 64; ++j) {
            float h = sb1[j];
            h = fmaf(sW1[4*j+0], q0, h);
            h = fmaf(sW1[4*j+1], q1, h);
            h = fmaf(sW1[4*j+2], q2, h);
            h = fmaxf(fmaf(sW1[4*j+3], q3, h), 0.0f);
            l0 = fmaf(sW2t[4*j+0], h, l0);
            l1 = fmaf(sW2t[4*j+1], h, l1);
            l2 = fmaf(sW2t[4*j+2], h, l2);
            l3 = fmaf(sW2t[4*j+3], h, l3);
        }
    }

    // ---- Phase A3: per-block batchnorm partials -> ws ----
    float v[8] = {l0, l1, l2, l3, l0*l0, l1*l1, l2*l2, l3*l3};
    #pragma unroll
    for (int off = 32; off >= 1; off >>= 1) {
        #pragma unroll
        for (int i = 0; i < 8; ++i) v[i] += __shfl_down(v[i], off);
    }
    const int lane = tid & 63, wv = tid >> 6;
    if (lane == 0) {
        #pragma unroll
        for (int i = 0; i < 8; ++i) sred[wv * 8 + i] = v[i];
    }
    __syncthreads();
    if (tid < 8) {
        part[blockIdx.x * 8 + tid] =
            sred[tid] + sred[tid + 8] + sred[tid + 16] + sred[tid + 24];
    }
    __threadfence();

    cg::this_grid().sync();

    // ---- Phase B: every block reduces gridDim.x*8 partials (L2-resident) ----
    const int total = gridDim.x * 8;
    float s = 0.f;
    for (int i = tid; i < total; i += 256) s += part[i];  // coalesced; channel = tid&7
    sred[tid] = s;
    __syncthreads();
    if (tid < 8) {
        float t = 0.f;
        #pragma unroll
        for (int j = 0; j < 32; ++j) t += sred[tid + 8 * j];
        sred[tid] = t;   // sred[0..3]=sum, sred[4..7]=sumsq
    }
    __syncthreads();
    if (tid < 4) {
        float mu   = sred[tid] * invB;
        float var  = sred[4 + tid] * invB - mu * mu;
        float rstd = 1.0f / sqrtf(var + 1e-5f);
        float gg   = gamma[tid] * rstd;
        sc[tid] = gg;
        sh[tid] = beta[tid] - mu * gg;
    }
    __syncthreads();

    if (active) {
        float4 o;
        o.x = fmaf(sc[0], l0, sh[0]);
        o.y = fmaf(sc[1], l1, sh[1]);
        o.z = fmaf(sc[2], l2, sh[2]);
        o.w = fmaf(sc[3], l3, sh[3]);
        ((float4*)out)[img] = o;
    }
}

extern "C" void kernel_launch(void* const* d_in, const int* in_sizes, int n_in,
                              void* d_out, int out_size, void* d_ws, size_t ws_size,
                              hipStream_t stream) {
    const float* x     = (const float*)d_in[0];
    const float* qp    = (const float*)d_in[1];
    const float* W1    = (const float*)d_in[2];
    const float* b1    = (const float*)d_in[3];
    const float* W2    = (const float*)d_in[4];
    const float* b2    = (const float*)d_in[5];
    const float* gamma = (const float*)d_in[6];
    const float* beta  = (const float*)d_in[7];
    float* out  = (float*)d_out;
    float* part = (float*)d_ws;

    int B = in_sizes[0] / 1296;                 // 65536
    float invB = 1.0f / (float)B;
    int nb = (B + IMGS_PER_BLOCK - 1) / IMGS_PER_BLOCK;  // 1024 blocks = 16 waves/CU

    void* args[] = {(void*)&x, (void*)&qp, (void*)&W1, (void*)&b1, (void*)&W2,
                    (void*)&b2, (void*)&gamma, (void*)&beta, (void*)&out,
                    (void*)&part, (void*)&B, (void*)&invB};
    hipLaunchCooperativeKernel((const void*)k_fused, dim3(nb), dim3(256),
                               args, 0, stream);
}

// Round 5
// 398.357 us; speedup vs baseline: 1.3129x; 1.3129x over previous
//
#include <hip/hip_runtime.h>
#include <math.h>

// Quantum circuit collapses analytically:
//   z_w = cos(q_params[w]) * cos(features[w])   (RZ layer = pure phase -> no-op on probs)
//   q_out = [z0, z0*z1, z0*z1*z2, z0*z1*z2*z3]  (CNOT chain = parity of independent bits)
// Then MLP 4->64 (relu) -> 4, batchnorm over batch.
//
// 2-kernel structure (R4 coop-kernel grid.sync regressed +126us -> avoid):
//   k_main: 1 thread = 1 image, 256 blocks. Pool+circuit+MLP, logits -> ws,
//           per-block batchnorm partials -> part[] (unconditional writes:
//           no init kernel, no atomics).
//   k_norm: each block reduces the 2048 L2-resident partials (8 KB), then
//           normalizes its 256 logits.

#define NBLK 256   // 65536 / 256 threads

__global__ __launch_bounds__(256) void k_main(
    const float* __restrict__ x,
    const float* __restrict__ qp,
    const float* __restrict__ W1,
    const float* __restrict__ b1,
    const float* __restrict__ W2,
    const float* __restrict__ b2,
    float* __restrict__ logits,
    float* __restrict__ part,   // NBLK*8 floats
    int B)
{
    __shared__ float sW1[256];   // [j][w], row-major 64x4
    __shared__ float sW2t[256];  // [j][k]  (transpose of W2 4x64)
    __shared__ float sb1[64];
    __shared__ float sred[32];   // 4 waves x 8 partials

    const int tid = threadIdx.x;
    sW1[tid]  = W1[tid];
    sW2t[tid] = W2[(tid & 3) * 64 + (tid >> 2)];
    if (tid < 64) sb1[tid] = b1[tid];
    __syncthreads();

    const int b = blockIdx.x * 256 + tid;
    float l0 = 0.f, l1 = 0.f, l2 = 0.f, l3 = 0.f;

    if (b < B) {
        const float* xb = x + (size_t)b * 1296;  // 36*36, rows 16B-aligned
        float f0 = 0.f, f1 = 0.f, f2 = 0.f, f3 = 0.f;
        #pragma unroll
        for (int r = 0; r < 6; ++r) {
            const float4* row = (const float4*)(xb + r * 36);
            float4 v0 = row[0], v1 = row[1], v2 = row[2];
            float4 v3 = row[3], v4 = row[4], v5 = row[5];
            f0 += v0.x + v0.y + v0.z + v0.w + v1.x + v1.y;  // cols 0..5
            f1 += v1.z + v1.w + v2.x + v2.y + v2.z + v2.w;  // cols 6..11
            f2 += v3.x + v3.y + v3.z + v3.w + v4.x + v4.y;  // cols 12..17
            f3 += v4.z + v4.w + v5.x + v5.y + v5.z + v5.w;  // cols 18..23
        }
        const float inv36 = 1.0f / 36.0f;
        float z0 = cosf(qp[0]) * cosf(f0 * inv36);
        float z1 = cosf(qp[1]) * cosf(f1 * inv36);
        float z2 = cosf(qp[2]) * cosf(f2 * inv36);
        float z3 = cosf(qp[3]) * cosf(f3 * inv36);
        float q0 = z0;
        float q1 = q0 * z1;
        float q2 = q1 * z2;
        float q3 = q2 * z3;

        l0 = b2[0]; l1 = b2[1]; l2 = b2[2]; l3 = b2[3];
        #pragma unroll 8
        for (int j = 0; j < 64; ++j) {
            float h = sb1[j];
            h = fmaf(sW1[4*j+0], q0, h);
            h = fmaf(sW1[4*j+1], q1, h);
            h = fmaf(sW1[4*j+2], q2, h);
            h = fmaxf(fmaf(sW1[4*j+3], q3, h), 0.0f);
            l0 = fmaf(sW2t[4*j+0], h, l0);
            l1 = fmaf(sW2t[4*j+1], h, l1);
            l2 = fmaf(sW2t[4*j+2], h, l2);
            l3 = fmaf(sW2t[4*j+3], h, l3);
        }
        ((float4*)logits)[b] = make_float4(l0, l1, l2, l3);
    }

    // per-block batchnorm partials (no atomics; every slot written every call)
    float v[8] = {l0, l1, l2, l3, l0*l0, l1*l1, l2*l2, l3*l3};
    #pragma unroll
    for (int off = 32; off >= 1; off >>= 1) {
        #pragma unroll
        for (int i = 0; i < 8; ++i) v[i] += __shfl_down(v[i], off);
    }
    const int lane = tid & 63, wv = tid >> 6;
    if (lane == 0) {
        #pragma unroll
        for (int i = 0; i < 8; ++i) sred[wv * 8 + i] = v[i];
    }
    __syncthreads();
    if (tid < 8) {
        part[blockIdx.x * 8 + tid] =
            sred[tid] + sred[tid + 8] + sred[tid + 16] + sred[tid + 24];
    }
}

__global__ __launch_bounds__(256) void k_norm(
    const float* __restrict__ logits,
    const float* __restrict__ part,
    const float* __restrict__ gamma,
    const float* __restrict__ beta,
    float* __restrict__ out,
    int B, float invB)
{
    __shared__ float sred[256];
    __shared__ float sc[4], sh[4];

    const int tid = threadIdx.x;

    // reduce NBLK*8 = 2048 partials; slot index mod 8 == tid mod 8 (256 % 8 == 0)
    float s = 0.f;
    #pragma unroll
    for (int it = 0; it < NBLK * 8 / 256; ++it) s += part[tid + 256 * it];
    sred[tid] = s;
    __syncthreads();
    if (tid < 8) {
        float t = 0.f;
        #pragma unroll
        for (int j = 0; j < 32; ++j) t += sred[tid + 8 * j];
        sred[tid] = t;   // [0..3]=sum, [4..7]=sumsq
    }
    __syncthreads();
    if (tid < 4) {
        float mu   = sred[tid] * invB;
        float var  = sred[4 + tid] * invB - mu * mu;
        float rstd = 1.0f / sqrtf(var + 1e-5f);
        float g = gamma[tid] * rstd;
        sc[tid] = g;
        sh[tid] = beta[tid] - mu * g;
    }
    __syncthreads();

    const int b = blockIdx.x * 256 + tid;
    if (b >= B) return;
    float4 l = ((const float4*)logits)[b];
    float4 o;
    o.x = fmaf(sc[0], l.x, sh[0]);
    o.y = fmaf(sc[1], l.y, sh[1]);
    o.z = fmaf(sc[2], l.z, sh[2]);
    o.w = fmaf(sc[3], l.w, sh[3]);
    ((float4*)out)[b] = o;
}

extern "C" void kernel_launch(void* const* d_in, const int* in_sizes, int n_in,
                              void* d_out, int out_size, void* d_ws, size_t ws_size,
                              hipStream_t stream) {
    const float* x     = (const float*)d_in[0];
    const float* qp    = (const float*)d_in[1];
    const float* W1    = (const float*)d_in[2];
    const float* b1    = (const float*)d_in[3];
    const float* W2    = (const float*)d_in[4];
    const float* b2    = (const float*)d_in[5];
    const float* gamma = (const float*)d_in[6];
    const float* beta  = (const float*)d_in[7];
    float* out = (float*)d_out;

    const int B = in_sizes[0] / 1296;            // 65536
    float* part   = (float*)d_ws;                // NBLK*8 floats
    float* logits = (float*)d_ws + 4096;         // B*4 floats, 16 KB offset (aligned)

    hipLaunchKernelGGL(k_main, dim3(NBLK), dim3(256), 0, stream,
                       x, qp, W1, b1, W2, b2, logits, part, B);
    hipLaunchKernelGGL(k_norm, dim3((B + 255) / 256), dim3(256), 0, stream,
                       logits, part, gamma, beta, out, B, 1.0f / (float)B);
}